// Round 3
// baseline (10866.036 us; speedup 1.0000x reference)
//
#include <hip/hip_runtime.h>
#include <hip/hip_bf16.h>

// Problem constants
#define BATCH 1024
#define SEQ   350
#define LAT   512
#define VOC   41
#define H0D   512
#define H1D   256
#define H2D   128
#define H3D   32
#define G1    768   // 3*H1D
#define G2    384   // 3*H2D
#define G3    96    // 3*H3D
#define SOS   1

// ws layout (floats). Sections same offsets/sizes as before, but matrix sections
// are now FUSED-GATE: [k][j][3] (gate innermost) so one dwordx3 feeds 3 gates.
#define O_HH0   0         // [256][256][3]
#define O_IH1   196608    // [256][128][3]
#define O_HH1   294912    // [128][128][3]
#define O_IH2   344064    // [128][32][3]
#define O_HH2   356352    // [32][32][3]
#define O_PROJ  359424    // [32][41]  (k-major, unchanged)
#define O_TAB   360736    // [41][256][3] fused-gate gi0 table
#define WS_FLOATS 392224

#define RT 4    // batch rows per block
#define NT 512  // threads per block (8 waves)

__global__ void setup_kernel(const float* __restrict__ Whh0, const float* __restrict__ Wih1,
                             const float* __restrict__ Whh1, const float* __restrict__ Wih2,
                             const float* __restrict__ Whh2, const float* __restrict__ Wproj,
                             const float* __restrict__ Wemb, const float* __restrict__ bemb,
                             const float* __restrict__ Wih0, const float* __restrict__ bih0,
                             float* __restrict__ ws) {
  int idx = blockIdx.x * blockDim.x + threadIdx.x;
  if (idx < 196608) {  // hh0 fused: idx = (k*256 + j)*3 + g
    int g = idx % 3, rem = idx / 3, j = rem % 256, k = rem / 256;
    ws[O_HH0 + idx] = Whh0[(g * 256 + j) * H1D + k];
    return;
  }
  idx -= 196608;
  if (idx < 98304) {   // ih1 fused: (k*128 + j)*3 + g, k<256
    int g = idx % 3, rem = idx / 3, j = rem % 128, k = rem / 128;
    ws[O_IH1 + idx] = Wih1[(g * 128 + j) * H1D + k];
    return;
  }
  idx -= 98304;
  if (idx < 49152) {   // hh1 fused: (k*128 + j)*3 + g, k<128
    int g = idx % 3, rem = idx / 3, j = rem % 128, k = rem / 128;
    ws[O_HH1 + idx] = Whh1[(g * 128 + j) * H2D + k];
    return;
  }
  idx -= 49152;
  if (idx < 12288) {   // ih2 fused: (k*32 + j)*3 + g, k<128
    int g = idx % 3, rem = idx / 3, j = rem % 32, k = rem / 32;
    ws[O_IH2 + idx] = Wih2[(g * 32 + j) * H2D + k];
    return;
  }
  idx -= 12288;
  if (idx < 3072) {    // hh2 fused: (k*32 + j)*3 + g, k<32
    int g = idx % 3, rem = idx / 3, j = rem % 32, k = rem / 32;
    ws[O_HH2 + idx] = Whh2[(g * 32 + j) * H3D + k];
    return;
  }
  idx -= 3072;
  if (idx < 1312) { int o = idx % VOC, k = idx / VOC; ws[O_PROJ + k*VOC + o] = Wproj[o*H3D + k]; return; }
  idx -= 1312;
  if (idx < 31488) {
    // gi0 table, fused-gate: idx = (v*256 + j)*3 + g; exact f64 accumulate.
    int g = idx % 3, rem = idx / 3, j = rem % 256, v = rem / 256;
    int o = g * 256 + j;
    double acc = (double)bih0[o];
    const float* wrow = Wih0 + (size_t)o * H0D;
    for (int k = 0; k < H0D; ++k)
      acc += ((double)Wemb[k*VOC + v] + (double)bemb[k]) * (double)wrow[k];
    ws[O_TAB + idx] = (float)acc;
  }
}

__device__ __forceinline__ float sigf(float x) { return 1.0f / (1.0f + expf(-x)); }

__global__ __launch_bounds__(NT, 2) void gru_persist(
    const float* __restrict__ latent, const int* __restrict__ tgt,
    const float* __restrict__ Winit, const float* __restrict__ binit,
    const float* __restrict__ bhh0,
    const float* __restrict__ bih1, const float* __restrict__ bhh1,
    const float* __restrict__ bih2, const float* __restrict__ bhh2,
    const float* __restrict__ bproj,
    const float* __restrict__ ws, float* __restrict__ out)
{
  const int tid = threadIdx.x;
  const int r0 = blockIdx.x * RT;

  const float* wt_hh0 = ws + O_HH0;
  const float* wt_ih1 = ws + O_IH1;
  const float* wt_hh1 = ws + O_HH1;
  const float* wt_ih2 = ws + O_IH2;
  const float* wt_hh2 = ws + O_HH2;
  const float* wt_proj = ws + O_PROJ;
  const float* tab = ws + O_TAB;

  float* __restrict__ out_logits = out;
  float* __restrict__ out_pred = out + (size_t)BATCH * SEQ * VOC;

  __shared__ __align__(16) float h0s[RT][H1D];     // 4 KB
  __shared__ __align__(16) float h1s[RT][H2D];     // 2 KB
  __shared__ __align__(16) float h2s[RT][H3D];     // 0.5 KB
  __shared__ float scA[2][RT][3][H1D];    // 24 KB  (both stage-A K-halves' partials)
  __shared__ float scBi[2][RT][3][H2D];   // 12 KB  (gi1 halves)
  __shared__ float scBh[2][RT][3][H2D];   // 12 KB  (gh1 halves)
  __shared__ float scC[10][3][RT][H3D];   // 15 KB  (stage C partials)
  __shared__ float projS[H3D * VOC];      // 5.1 KB
  __shared__ int   toksAll[RT][SEQ];      // 5.5 KB
  // total ~80 KB -> 1 block/CU (grid == 256 CUs anyway)

  const int j  = tid & 255;
  const int kh = tid >> 8;
  const int jb = tid & 127;
  const int g  = tid >> 7;
  const int jc = tid & 31;
  const int sc = tid >> 5;   // 0..15
  const int wv = tid >> 6;   // wave id 0..7
  const int lane = tid & 63;

  // ---- t-invariant f32 biases
  const float bA_r = bhh0[j], bA_z = bhh0[256 + j], bA_n = bhh0[512 + j];
  const float bB_ir = bih1[jb], bB_iz = bih1[128 + jb], bB_in = bih1[256 + jb];
  const float bB_hr = bhh1[jb], bB_hz = bhh1[128 + jb], bB_hn = bhh1[256 + jb];
  const int jj2 = lane & 31;
  const float bC_ir = bih2[jj2], bC_iz = bih2[32 + jj2], bC_in = bih2[64 + jj2];
  const float bC_hr = bhh2[jj2], bC_hz = bhh2[32 + jj2], bC_hn = bhh2[64 + jj2];
  const int cpr = (lane < VOC) ? lane : 0;
  const float bP = bproj[cpr];

  // ---- one-time staging: tokens (SOS at t=0) and projection weights into LDS
  for (int i = tid; i < RT * SEQ; i += NT) {
    int r = i / SEQ, tt = i - r * SEQ;
    toksAll[r][tt] = (tt == 0) ? SOS : tgt[(size_t)(r0 + r) * SEQ + tt];
  }
  for (int i = tid; i < H3D * VOC; i += NT) projS[i] = wt_proj[i];

  // ---- init hidden states: combined = latent @ Winit.T + binit (f64, one-time;
  //      keeps early-step logits — which set absmax — exact)
  for (int idx = tid; idx < RT * 416; idx += NT) {
    int r = idx / 416, jj = idx - r * 416;
    const float* lrow = latent + (size_t)(r0 + r) * LAT;
    const float* wrow = Winit + (size_t)jj * LAT;
    double acc = (double)binit[jj];
    for (int k = 0; k < LAT; ++k) acc += (double)lrow[k] * (double)wrow[k];
    float a = (float)acc;
    if (jj < H1D) h0s[r][jj] = a;
    else if (jj < H1D + H2D) h1s[r][jj - H1D] = a;
    else h2s[r][jj - H1D - H2D] = a;
  }
  __syncthreads();

  for (int t = 0; t < SEQ; ++t) {
    // ======== Stage A: GRU0. j = tid&255; kh = K-half. Both halves write scA;
    //          epilogue rows split kh0->{0,1}, kh1->{2,3}. ========
    {
      // prefetch this thread's two tab rows (consumed after B1; overlaps FMA loop)
      const int er0 = 2 * kh, er1 = er0 + 1;
      const int tok0 = toksAll[er0][t], tok1 = toksAll[er1][t];
      const float3 tv0 = *(const float3*)(tab + (tok0 * 256 + j) * 3);
      const float3 tv1 = *(const float3*)(tab + (tok1 * 256 + j) * 3);

      float aR[RT], aZ[RT], aN[RT];
      #pragma unroll
      for (int r = 0; r < RT; ++r) { aR[r] = 0.0f; aZ[r] = 0.0f; aN[r] = 0.0f; }
      const int k0 = kh * 128;
      const float* wp = wt_hh0 + (k0 * 256 + j) * 3;
      for (int kb = 0; kb < 128; kb += 4) {
        float4 hv[RT];
        #pragma unroll
        for (int r = 0; r < RT; ++r) hv[r] = *(const float4*)&h0s[r][k0 + kb];
        #pragma unroll
        for (int u = 0; u < 4; ++u) {
          const float3 w = *(const float3*)wp; wp += 768;
          #pragma unroll
          for (int r = 0; r < RT; ++r) {
            const float hval = ((const float*)&hv[r])[u];
            aR[r] = fmaf(hval, w.x, aR[r]);
            aZ[r] = fmaf(hval, w.y, aZ[r]);
            aN[r] = fmaf(hval, w.z, aN[r]);
          }
        }
      }
      #pragma unroll
      for (int r = 0; r < RT; ++r) {
        scA[kh][r][0][j] = aR[r];
        scA[kh][r][1][j] = aZ[r];
        scA[kh][r][2][j] = aN[r];
      }
      __syncthreads();  // B1: scA both halves visible; all h0s reads done
      {
        const int oth = 1 - kh;
        #pragma unroll
        for (int e = 0; e < 2; ++e) {
          const int r = er0 + e;
          const float3 tv = e ? tv1 : tv0;
          const float gR  = tv.x + aR[r] + scA[oth][r][0][j] + bA_r;
          const float gZ  = tv.y + aZ[r] + scA[oth][r][1][j] + bA_z;
          const float ghN =        aN[r] + scA[oth][r][2][j] + bA_n;
          const float rg = sigf(gR);
          const float zg = sigf(gZ);
          const float ng = tanhf(fmaf(rg, ghN, tv.z));
          h0s[r][j] = (1.0f - zg) * ng + zg * h0s[r][j];
        }
      }
    }
    __syncthreads();  // B2: h0s new visible

    // ======== Stage B: GRU1. jb = tid&127; g0,g1 = gi1 K-halves (new h0s),
    //          g2,g3 = gh1 K-halves (old h1s). Epilogue on light waves g2/g3. ========
    {
      float bR[RT], bZ[RT], bN[RT];
      #pragma unroll
      for (int r = 0; r < RT; ++r) { bR[r] = 0.0f; bZ[r] = 0.0f; bN[r] = 0.0f; }
      if (g < 2) {
        const int k0 = g * 128;
        const float* wp = wt_ih1 + (k0 * 128 + jb) * 3;
        for (int kb = 0; kb < 128; kb += 4) {
          float4 hv[RT];
          #pragma unroll
          for (int r = 0; r < RT; ++r) hv[r] = *(const float4*)&h0s[r][k0 + kb];
          #pragma unroll
          for (int u = 0; u < 4; ++u) {
            const float3 w = *(const float3*)wp; wp += 384;
            #pragma unroll
            for (int r = 0; r < RT; ++r) {
              const float hval = ((const float*)&hv[r])[u];
              bR[r] = fmaf(hval, w.x, bR[r]);
              bZ[r] = fmaf(hval, w.y, bZ[r]);
              bN[r] = fmaf(hval, w.z, bN[r]);
            }
          }
        }
        #pragma unroll
        for (int r = 0; r < RT; ++r) {
          scBi[g][r][0][jb] = bR[r];
          scBi[g][r][1][jb] = bZ[r];
          scBi[g][r][2][jb] = bN[r];
        }
      } else {
        const int k0 = (g - 2) * 64;
        const float* wp = wt_hh1 + (k0 * 128 + jb) * 3;
        for (int kb = 0; kb < 64; kb += 4) {
          float4 hv[RT];
          #pragma unroll
          for (int r = 0; r < RT; ++r) hv[r] = *(const float4*)&h1s[r][k0 + kb];
          #pragma unroll
          for (int u = 0; u < 4; ++u) {
            const float3 w = *(const float3*)wp; wp += 384;
            #pragma unroll
            for (int r = 0; r < RT; ++r) {
              const float hval = ((const float*)&hv[r])[u];
              bR[r] = fmaf(hval, w.x, bR[r]);
              bZ[r] = fmaf(hval, w.y, bZ[r]);
              bN[r] = fmaf(hval, w.z, bN[r]);
            }
          }
        }
        #pragma unroll
        for (int r = 0; r < RT; ++r) {
          scBh[g - 2][r][0][jb] = bR[r];
          scBh[g - 2][r][1][jb] = bZ[r];
          scBh[g - 2][r][2][jb] = bN[r];
        }
      }
      __syncthreads();  // B3: partials visible; all h0s/h1s reads done
      if (g >= 2) {
        const int rb = (g - 2) * 2;
        const int oh = 3 - g;   // other gh half's scBh slot
        #pragma unroll
        for (int e = 0; e < 2; ++e) {
          const int r = rb + e;
          const float giR = scBi[0][r][0][jb] + scBi[1][r][0][jb] + bB_ir;
          const float giZ = scBi[0][r][1][jb] + scBi[1][r][1][jb] + bB_iz;
          const float giN = scBi[0][r][2][jb] + scBi[1][r][2][jb] + bB_in;
          const float ghR = bR[r] + scBh[oh][r][0][jb] + bB_hr;
          const float ghZ = bZ[r] + scBh[oh][r][1][jb] + bB_hz;
          const float ghN = bN[r] + scBh[oh][r][2][jb] + bB_hn;
          const float rg = sigf(giR + ghR);
          const float zg = sigf(giZ + ghZ);
          const float ng = tanhf(fmaf(rg, ghN, giN));
          h1s[r][jb] = (1.0f - zg) * ng + zg * h1s[r][jb];
        }
      }
    }
    __syncthreads();  // B4: h1s new visible

    // ======== Stage C: GRU2. jc = tid&31; sc0..7 = gi2 K-slices (new h1s),
    //          sc8,9 = gh2 K-slices (old h2s). ========
    {
      float cR[RT], cZ[RT], cN[RT];
      #pragma unroll
      for (int r = 0; r < RT; ++r) { cR[r] = 0.0f; cZ[r] = 0.0f; cN[r] = 0.0f; }
      if (sc < 8) {
        const int k0 = sc * 16;
        const float* wp = wt_ih2 + (k0 * 32 + jc) * 3;
        for (int kk = 0; kk < 16; ++kk) {
          const float3 w = *(const float3*)wp; wp += 96;
          #pragma unroll
          for (int r = 0; r < RT; ++r) {
            const float hval = h1s[r][k0 + kk];
            cR[r] = fmaf(hval, w.x, cR[r]);
            cZ[r] = fmaf(hval, w.y, cZ[r]);
            cN[r] = fmaf(hval, w.z, cN[r]);
          }
        }
      } else if (sc < 10) {
        const int k0 = (sc - 8) * 16;
        const float* wp = wt_hh2 + (k0 * 32 + jc) * 3;
        for (int kk = 0; kk < 16; ++kk) {
          const float3 w = *(const float3*)wp; wp += 96;
          #pragma unroll
          for (int r = 0; r < RT; ++r) {
            const float hval = h2s[r][k0 + kk];
            cR[r] = fmaf(hval, w.x, cR[r]);
            cZ[r] = fmaf(hval, w.y, cZ[r]);
            cN[r] = fmaf(hval, w.z, cN[r]);
          }
        }
      }
      if (sc < 10) {
        #pragma unroll
        for (int r = 0; r < RT; ++r) {
          scC[sc][0][r][jc] = cR[r];
          scC[sc][1][r][jc] = cZ[r];
          scC[sc][2][r][jc] = cN[r];
        }
      }
    }
    __syncthreads();  // B5: scC partials visible; all h2s(old) reads done

    // ======== Stage C combine + projection + argmax, waves 0-3 (one row each);
    //          waves 4-7 fall through into stage A of t+1 (sync via B1(t+1)). ========
    if (wv < 4) {
      const int r = wv;
      float h2f = 0.0f;
      if (lane < 32) {
        const int jj = lane;
        float giR = bC_ir, giZ = bC_iz, giN = bC_in;
        #pragma unroll
        for (int s = 0; s < 8; ++s) {
          giR += scC[s][0][r][jj];
          giZ += scC[s][1][r][jj];
          giN += scC[s][2][r][jj];
        }
        const float ghR = scC[8][0][r][jj] + scC[9][0][r][jj] + bC_hr;
        const float ghZ = scC[8][1][r][jj] + scC[9][1][r][jj] + bC_hz;
        const float ghN = scC[8][2][r][jj] + scC[9][2][r][jj] + bC_hn;
        const float rg = sigf(giR + ghR);
        const float zg = sigf(giZ + ghZ);
        const float ng = tanhf(fmaf(rg, ghN, giN));
        h2f = (1.0f - zg) * ng + zg * h2s[r][jj];
        h2s[r][jj] = h2f;   // next reader (sc8,9 at t+1) is >=3 barriers away
      }
      // projection: lane c computes logit c; h2 broadcast from lanes 0..31
      float acc = bP;
      #pragma unroll
      for (int k = 0; k < H3D; ++k) {
        const float hk = __shfl(h2f, k);
        acc = fmaf(hk, projS[k * VOC + cpr], acc);
      }
      if (lane < VOC)
        out_logits[((size_t)(r0 + r) * SEQ + t) * VOC + lane] = acc;
      // wave-wide argmax, first-max (lowest index) tie-break to match jnp.argmax
      float val = (lane < VOC) ? acc : -3.402823466e38f;
      int idx = lane;
      #pragma unroll
      for (int off = 32; off > 0; off >>= 1) {
        const float ov = __shfl_xor(val, off);
        const int   oi = __shfl_xor(idx, off);
        if (ov > val || (ov == val && oi < idx)) { val = ov; idx = oi; }
      }
      if (lane == 0)
        out_pred[(size_t)(r0 + r) * SEQ + t] = (float)idx;
    }
    // Hazard audit (writer(t+1) vs reader(t)):
    //  scA[kh]: W after B1(t+1) / R between B1(t) and B2(t) — >=4 barriers — OK
    //  h0s: W after B1(t+1) / last R before B3(t) — OK
    //  scBi/scBh: W before B3(t+1) / R between B3(t) and B4(t) — OK
    //  h1s: W between B3(t+1) and B4(t+1) / last R before B5(t) (stage C gi2 reads
    //       h1s(t) before B5... note stage C(t+1) reads h1s(t+1) after B4(t+1)) — OK
    //  h2s: W after B5(t) by waves 0-3 / R by wave 4 between B4(t+1) and B5(t+1) — OK
    //  scC: W between B4(t+1) and B5(t+1) / R right after B5(t) — OK
    //  toksAll/projS: read-only after init — OK
  }
}

extern "C" void kernel_launch(void* const* d_in, const int* in_sizes, int n_in,
                              void* d_out, int out_size, void* d_ws, size_t ws_size,
                              hipStream_t stream) {
  const float* latent  = (const float*)d_in[0];
  const int*   tgt     = (const int*)d_in[1];
  const float* Wemb    = (const float*)d_in[2];
  const float* bemb    = (const float*)d_in[3];
  const float* Winit   = (const float*)d_in[4];
  const float* binit   = (const float*)d_in[5];
  const float* Wih0    = (const float*)d_in[6];
  const float* Whh0    = (const float*)d_in[7];
  const float* bih0    = (const float*)d_in[8];
  const float* bhh0    = (const float*)d_in[9];
  const float* Wih1    = (const float*)d_in[10];
  const float* Whh1    = (const float*)d_in[11];
  const float* bih1    = (const float*)d_in[12];
  const float* bhh1    = (const float*)d_in[13];
  const float* Wih2    = (const float*)d_in[14];
  const float* Whh2    = (const float*)d_in[15];
  const float* bih2    = (const float*)d_in[16];
  const float* bhh2    = (const float*)d_in[17];
  const float* Wproj   = (const float*)d_in[18];
  const float* bproj   = (const float*)d_in[19];

  float* ws = (float*)d_ws;
  float* out = (float*)d_out;

  int setup_threads = WS_FLOATS;
  int setup_blocks = (setup_threads + 255) / 256;
  setup_kernel<<<setup_blocks, 256, 0, stream>>>(Whh0, Wih1, Whh1, Wih2, Whh2, Wproj,
                                                Wemb, bemb, Wih0, bih0, ws);

  gru_persist<<<BATCH / RT, NT, 0, stream>>>(latent, tgt, Winit, binit,
                                             bhh0, bih1, bhh1, bih2, bhh2, bproj,
                                             ws, out);
}

// Round 7
// 6786.114 us; speedup vs baseline: 1.6012x; 1.6012x over previous
//
#include <hip/hip_runtime.h>
#include <hip/hip_bf16.h>

// Problem constants
#define BATCH 1024
#define SEQ   350
#define LAT   512
#define VOC   41
#define H0D   512
#define H1D   256
#define H2D   128
#define H3D   32
#define G1    768   // 3*H1D
#define G2    384   // 3*H2D
#define G3    96    // 3*H3D
#define SOS   1

// ws layout (floats) — PLANAR, identical to round-2 (proven L2-resident: 28 MB FETCH)
#define O_HH0   0         // wt_hh0 [256][768]   (k-major, gate planes at +0/+256/+512)
#define O_IH1   196608    // wt_ih1 [256][384]
#define O_HH1   294912    // wt_hh1 [128][384]
#define O_IH2   344064    // wt_ih2 [128][96]
#define O_HH2   356352    // wt_hh2 [32][96]
#define O_PROJ  359424    // wt_proj [32][41]
#define O_TAB   360736    // gi0 table [41][768]
#define WS_FLOATS 392224

#define RT 4    // batch rows per block
#define NT 512  // threads per block (8 waves)

__global__ void setup_kernel(const float* __restrict__ Whh0, const float* __restrict__ Wih1,
                             const float* __restrict__ Whh1, const float* __restrict__ Wih2,
                             const float* __restrict__ Whh2, const float* __restrict__ Wproj,
                             const float* __restrict__ Wemb, const float* __restrict__ bemb,
                             const float* __restrict__ Wih0, const float* __restrict__ bih0,
                             float* __restrict__ ws) {
  int idx = blockIdx.x * blockDim.x + threadIdx.x;
  if (idx < 196608) { int o = idx % G1, k = idx / G1; ws[O_HH0 + k*G1 + o] = Whh0[o*H1D + k]; return; }
  idx -= 196608;
  if (idx < 98304)  { int o = idx % G2, k = idx / G2; ws[O_IH1 + k*G2 + o] = Wih1[o*H1D + k]; return; }
  idx -= 98304;
  if (idx < 49152)  { int o = idx % G2, k = idx / G2; ws[O_HH1 + k*G2 + o] = Whh1[o*H2D + k]; return; }
  idx -= 49152;
  if (idx < 12288)  { int o = idx % G3, k = idx / G3; ws[O_IH2 + k*G3 + o] = Wih2[o*H2D + k]; return; }
  idx -= 12288;
  if (idx < 3072)   { int o = idx % G3, k = idx / G3; ws[O_HH2 + k*G3 + o] = Whh2[o*H3D + k]; return; }
  idx -= 3072;
  if (idx < 1312)   { int o = idx % VOC, k = idx / VOC; ws[O_PROJ + k*VOC + o] = Wproj[o*H3D + k]; return; }
  idx -= 1312;
  if (idx < 31488) {
    // gi0 table: exact (f64-accumulated) x@Wih0.T + bih0 per token value.
    int o = idx % G1, v = idx / G1;
    double acc = (double)bih0[o];
    const float* wrow = Wih0 + (size_t)o * H0D;
    for (int k = 0; k < H0D; ++k)
      acc += ((double)Wemb[k*VOC + v] + (double)bemb[k]) * (double)wrow[k];
    ws[O_TAB + v*G1 + o] = (float)acc;
  }
}

__device__ __forceinline__ float sigf(float x) { return 1.0f / (1.0f + expf(-x)); }

__global__ __launch_bounds__(NT, 2) void gru_persist(
    const float* __restrict__ latent, const int* __restrict__ tgt,
    const float* __restrict__ Winit, const float* __restrict__ binit,
    const float* __restrict__ bhh0,
    const float* __restrict__ bih1, const float* __restrict__ bhh1,
    const float* __restrict__ bih2, const float* __restrict__ bhh2,
    const float* __restrict__ bproj,
    const float* __restrict__ ws, float* __restrict__ out)
{
  const int tid = threadIdx.x;
  const int r0 = blockIdx.x * RT;

  const float* wt_hh0 = ws + O_HH0;
  const float* wt_ih1 = ws + O_IH1;
  const float* wt_hh1 = ws + O_HH1;
  const float* wt_ih2 = ws + O_IH2;
  const float* wt_hh2 = ws + O_HH2;
  const float* wt_proj = ws + O_PROJ;
  const float* tab = ws + O_TAB;

  float* __restrict__ out_logits = out;
  float* __restrict__ out_pred = out + (size_t)BATCH * SEQ * VOC;

  __shared__ __align__(16) float h0s[RT][H1D];     // 4 KB
  __shared__ __align__(16) float h1s[RT][H2D];     // 2 KB
  __shared__ __align__(16) float h2s[RT][H3D];     // 0.5 KB
  __shared__ float scA[2][RT][3][H1D];    // 24 KB  (both stage-A K-halves' partials)
  __shared__ float scBi[2][RT][3][H2D];   // 12 KB  (gi1 halves)
  __shared__ float scBh[2][RT][3][H2D];   // 12 KB  (gh1 halves)
  __shared__ float scC[10][3][RT][H3D];   // 15 KB  (stage C partials)
  __shared__ float projS[H3D * VOC];      // 5.1 KB
  __shared__ int   toksAll[RT][SEQ];      // 5.5 KB
  // total ~80 KB -> 1 block/CU (grid == 256 CUs anyway)

  const int j  = tid & 255;
  const int kh = tid >> 8;
  const int jb = tid & 127;
  const int g  = tid >> 7;
  const int jc = tid & 31;
  const int sc = tid >> 5;   // 0..15
  const int wv = tid >> 6;   // wave id 0..7
  const int lane = tid & 63;

  // ---- t-invariant f32 biases (f32 epilogues proven bit-equal absmax in R3)
  const float bA_r = bhh0[j], bA_z = bhh0[256 + j], bA_n = bhh0[512 + j];
  const float bB_ir = bih1[jb], bB_iz = bih1[128 + jb], bB_in = bih1[256 + jb];
  const float bB_hr = bhh1[jb], bB_hz = bhh1[128 + jb], bB_hn = bhh1[256 + jb];
  const int jj2 = lane & 31;
  const float bC_ir = bih2[jj2], bC_iz = bih2[32 + jj2], bC_in = bih2[64 + jj2];
  const float bC_hr = bhh2[jj2], bC_hz = bhh2[32 + jj2], bC_hn = bhh2[64 + jj2];
  const int cpr = (lane < VOC) ? lane : 0;
  const float bP = bproj[cpr];

  // ---- one-time staging: tokens (SOS at t=0) and projection weights into LDS
  for (int i = tid; i < RT * SEQ; i += NT) {
    int r = i / SEQ, tt = i - r * SEQ;
    toksAll[r][tt] = (tt == 0) ? SOS : tgt[(size_t)(r0 + r) * SEQ + tt];
  }
  for (int i = tid; i < H3D * VOC; i += NT) projS[i] = wt_proj[i];

  // ---- init hidden states: combined = latent @ Winit.T + binit (f64, one-time;
  //      keeps early-step logits — which set absmax — exact)
  for (int idx = tid; idx < RT * 416; idx += NT) {
    int r = idx / 416, jj = idx - r * 416;
    const float* lrow = latent + (size_t)(r0 + r) * LAT;
    const float* wrow = Winit + (size_t)jj * LAT;
    double acc = (double)binit[jj];
    for (int k = 0; k < LAT; ++k) acc += (double)lrow[k] * (double)wrow[k];
    float a = (float)acc;
    if (jj < H1D) h0s[r][jj] = a;
    else if (jj < H1D + H2D) h1s[r][jj - H1D] = a;
    else h2s[r][jj - H1D - H2D] = a;
  }
  __syncthreads();

  for (int t = 0; t < SEQ; ++t) {
    // ======== Stage A: GRU0. j = tid&255; kh = K-half. Both halves write scA;
    //          epilogue rows split kh0->{0,1}, kh1->{2,3}. ========
    {
      // prefetch this thread's two tab rows (planar; consumed after B1, overlaps FMAs)
      const int er0 = 2 * kh, er1 = er0 + 1;
      const float* trow0 = tab + (size_t)toksAll[er0][t] * G1;
      const float* trow1 = tab + (size_t)toksAll[er1][t] * G1;
      const float tv0x = trow0[j], tv0y = trow0[256 + j], tv0z = trow0[512 + j];
      const float tv1x = trow1[j], tv1y = trow1[256 + j], tv1z = trow1[512 + j];

      float aR[RT], aZ[RT], aN[RT];
      #pragma unroll
      for (int r = 0; r < RT; ++r) { aR[r] = 0.0f; aZ[r] = 0.0f; aN[r] = 0.0f; }
      const float* __restrict__ wbase = wt_hh0 + j;
      const int k0 = kh * 128;
      for (int kb = k0; kb < k0 + 128; kb += 4) {
        float4 hv[RT];
        #pragma unroll
        for (int r = 0; r < RT; ++r) hv[r] = *(const float4*)&h0s[r][kb];
        #pragma unroll
        for (int u = 0; u < 4; ++u) {
          const float* wp = wbase + (size_t)(kb + u) * G1;
          const float wr = wp[0], wz = wp[256], wn = wp[512];
          #pragma unroll
          for (int r = 0; r < RT; ++r) {
            const float hval = ((const float*)&hv[r])[u];
            aR[r] = fmaf(hval, wr, aR[r]);
            aZ[r] = fmaf(hval, wz, aZ[r]);
            aN[r] = fmaf(hval, wn, aN[r]);
          }
        }
      }
      #pragma unroll
      for (int r = 0; r < RT; ++r) {
        scA[kh][r][0][j] = aR[r];
        scA[kh][r][1][j] = aZ[r];
        scA[kh][r][2][j] = aN[r];
      }
      __syncthreads();  // B1: scA both halves visible; all h0s reads done
      {
        const int oth = 1 - kh;
        #pragma unroll
        for (int e = 0; e < 2; ++e) {
          const int r = er0 + e;
          const float tx = e ? tv1x : tv0x;
          const float ty = e ? tv1y : tv0y;
          const float tz = e ? tv1z : tv0z;
          const float gR  = tx + aR[r] + scA[oth][r][0][j] + bA_r;
          const float gZ  = ty + aZ[r] + scA[oth][r][1][j] + bA_z;
          const float ghN =      aN[r] + scA[oth][r][2][j] + bA_n;
          const float rg = sigf(gR);
          const float zg = sigf(gZ);
          const float ng = tanhf(fmaf(rg, ghN, tz));
          h0s[r][j] = (1.0f - zg) * ng + zg * h0s[r][j];
        }
      }
    }
    __syncthreads();  // B2: h0s new visible

    // ======== Stage B: GRU1. jb = tid&127; g0,g1 = gi1 K-halves (new h0s),
    //          g2,g3 = gh1 K-halves (old h1s). Epilogue on light waves g2/g3. ========
    {
      float bR[RT], bZ[RT], bN[RT];
      #pragma unroll
      for (int r = 0; r < RT; ++r) { bR[r] = 0.0f; bZ[r] = 0.0f; bN[r] = 0.0f; }
      if (g < 2) {
        const float* __restrict__ wbase = wt_ih1 + jb;
        const int k0 = g * 128;
        for (int kb = k0; kb < k0 + 128; kb += 4) {
          float4 hv[RT];
          #pragma unroll
          for (int r = 0; r < RT; ++r) hv[r] = *(const float4*)&h0s[r][kb];
          #pragma unroll
          for (int u = 0; u < 4; ++u) {
            const float* wp = wbase + (size_t)(kb + u) * G2;
            const float wr = wp[0], wz = wp[128], wn = wp[256];
            #pragma unroll
            for (int r = 0; r < RT; ++r) {
              const float hval = ((const float*)&hv[r])[u];
              bR[r] = fmaf(hval, wr, bR[r]);
              bZ[r] = fmaf(hval, wz, bZ[r]);
              bN[r] = fmaf(hval, wn, bN[r]);
            }
          }
        }
        #pragma unroll
        for (int r = 0; r < RT; ++r) {
          scBi[g][r][0][jb] = bR[r];
          scBi[g][r][1][jb] = bZ[r];
          scBi[g][r][2][jb] = bN[r];
        }
      } else {
        const float* __restrict__ wbase = wt_hh1 + jb;
        const int k0 = (g - 2) * 64;
        for (int kb = k0; kb < k0 + 64; kb += 4) {
          float4 hv[RT];
          #pragma unroll
          for (int r = 0; r < RT; ++r) hv[r] = *(const float4*)&h1s[r][kb];
          #pragma unroll
          for (int u = 0; u < 4; ++u) {
            const float* wp = wbase + (size_t)(kb + u) * G2;
            const float wr = wp[0], wz = wp[128], wn = wp[256];
            #pragma unroll
            for (int r = 0; r < RT; ++r) {
              const float hval = ((const float*)&hv[r])[u];
              bR[r] = fmaf(hval, wr, bR[r]);
              bZ[r] = fmaf(hval, wz, bZ[r]);
              bN[r] = fmaf(hval, wn, bN[r]);
            }
          }
        }
        #pragma unroll
        for (int r = 0; r < RT; ++r) {
          scBh[g - 2][r][0][jb] = bR[r];
          scBh[g - 2][r][1][jb] = bZ[r];
          scBh[g - 2][r][2][jb] = bN[r];
        }
      }
      __syncthreads();  // B3: partials visible; all h0s/h1s reads done
      if (g >= 2) {
        const int rb = (g - 2) * 2;
        const int oh = 3 - g;   // other gh half's scBh slot
        #pragma unroll
        for (int e = 0; e < 2; ++e) {
          const int r = rb + e;
          const float giR = scBi[0][r][0][jb] + scBi[1][r][0][jb] + bB_ir;
          const float giZ = scBi[0][r][1][jb] + scBi[1][r][1][jb] + bB_iz;
          const float giN = scBi[0][r][2][jb] + scBi[1][r][2][jb] + bB_in;
          const float ghR = bR[r] + scBh[oh][r][0][jb] + bB_hr;
          const float ghZ = bZ[r] + scBh[oh][r][1][jb] + bB_hz;
          const float ghN = bN[r] + scBh[oh][r][2][jb] + bB_hn;
          const float rg = sigf(giR + ghR);
          const float zg = sigf(giZ + ghZ);
          const float ng = tanhf(fmaf(rg, ghN, giN));
          h1s[r][jb] = (1.0f - zg) * ng + zg * h1s[r][jb];
        }
      }
    }
    __syncthreads();  // B4: h1s new visible

    // ======== Stage C: GRU2. jc = tid&31; sc0..7 = gi2 K-slices (new h1s),
    //          sc8,9 = gh2 K-slices (old h2s). ========
    {
      float cR[RT], cZ[RT], cN[RT];
      #pragma unroll
      for (int r = 0; r < RT; ++r) { cR[r] = 0.0f; cZ[r] = 0.0f; cN[r] = 0.0f; }
      if (sc < 8) {
        for (int kk = 0; kk < 16; ++kk) {
          int k = sc * 16 + kk;
          const float* wp = wt_ih2 + (size_t)k * G3;
          const float wr = wp[jc], wz = wp[32 + jc], wn = wp[64 + jc];
          #pragma unroll
          for (int r = 0; r < RT; ++r) {
            const float hval = h1s[r][k];
            cR[r] = fmaf(hval, wr, cR[r]);
            cZ[r] = fmaf(hval, wz, cZ[r]);
            cN[r] = fmaf(hval, wn, cN[r]);
          }
        }
      } else if (sc < 10) {
        for (int kk = 0; kk < 16; ++kk) {
          int k = (sc - 8) * 16 + kk;
          const float* wp = wt_hh2 + (size_t)k * G3;
          const float wr = wp[jc], wz = wp[32 + jc], wn = wp[64 + jc];
          #pragma unroll
          for (int r = 0; r < RT; ++r) {
            const float hval = h2s[r][k];
            cR[r] = fmaf(hval, wr, cR[r]);
            cZ[r] = fmaf(hval, wz, cZ[r]);
            cN[r] = fmaf(hval, wn, cN[r]);
          }
        }
      }
      if (sc < 10) {
        #pragma unroll
        for (int r = 0; r < RT; ++r) {
          scC[sc][0][r][jc] = cR[r];
          scC[sc][1][r][jc] = cZ[r];
          scC[sc][2][r][jc] = cN[r];
        }
      }
    }
    __syncthreads();  // B5: scC partials visible; all h2s(old) reads done

    // ======== Stage C combine + projection + argmax, waves 0-3 (one row each);
    //          waves 4-7 fall through into stage A of t+1 (sync via B1(t+1)). ========
    if (wv < 4) {
      const int r = wv;
      float h2f = 0.0f;
      if (lane < 32) {
        const int jj = lane;
        float giR = bC_ir, giZ = bC_iz, giN = bC_in;
        #pragma unroll
        for (int s = 0; s < 8; ++s) {
          giR += scC[s][0][r][jj];
          giZ += scC[s][1][r][jj];
          giN += scC[s][2][r][jj];
        }
        const float ghR = scC[8][0][r][jj] + scC[9][0][r][jj] + bC_hr;
        const float ghZ = scC[8][1][r][jj] + scC[9][1][r][jj] + bC_hz;
        const float ghN = scC[8][2][r][jj] + scC[9][2][r][jj] + bC_hn;
        const float rg = sigf(giR + ghR);
        const float zg = sigf(giZ + ghZ);
        const float ng = tanhf(fmaf(rg, ghN, giN));
        h2f = (1.0f - zg) * ng + zg * h2s[r][jj];
        h2s[r][jj] = h2f;   // next reader (sc8,9 at t+1) is >=3 barriers away
      }
      // projection: lane c computes logit c; h2 broadcast from lanes 0..31
      float acc = bP;
      #pragma unroll
      for (int k = 0; k < H3D; ++k) {
        const float hk = __shfl(h2f, k);
        acc = fmaf(hk, projS[k * VOC + cpr], acc);
      }
      if (lane < VOC)
        out_logits[((size_t)(r0 + r) * SEQ + t) * VOC + lane] = acc;
      // wave-wide argmax, first-max (lowest index) tie-break to match jnp.argmax
      float val = (lane < VOC) ? acc : -3.402823466e38f;
      int idx = lane;
      #pragma unroll
      for (int off = 32; off > 0; off >>= 1) {
        const float ov = __shfl_xor(val, off);
        const int   oi = __shfl_xor(idx, off);
        if (ov > val || (ov == val && oi < idx)) { val = ov; idx = oi; }
      }
      if (lane == 0)
        out_pred[(size_t)(r0 + r) * SEQ + t] = (float)idx;
    }
    // Hazard audit (writer(t+1) vs reader(t)):
    //  scA[kh]: W after B1(t+1) / R between B1(t) and B2(t) — >=4 barriers — OK
    //  h0s: W after B1(t+1) / last R before B3(t) — OK
    //  scBi/scBh: W before B3(t+1) / R between B3(t) and B4(t) — OK
    //  h1s: W between B3(t+1) and B4(t+1) / last R before B5(t) — OK
    //  h2s: W after B5(t) by waves 0-3 / R by sc8,9 between B4(t+1) and B5(t+1) — OK
    //  scC: W between B4(t+1) and B5(t+1) / R right after B5(t) — OK
    //  toksAll/projS: read-only after init — OK
  }
}

extern "C" void kernel_launch(void* const* d_in, const int* in_sizes, int n_in,
                              void* d_out, int out_size, void* d_ws, size_t ws_size,
                              hipStream_t stream) {
  const float* latent  = (const float*)d_in[0];
  const int*   tgt     = (const int*)d_in[1];
  const float* Wemb    = (const float*)d_in[2];
  const float* bemb    = (const float*)d_in[3];
  const float* Winit   = (const float*)d_in[4];
  const float* binit   = (const float*)d_in[5];
  const float* Wih0    = (const float*)d_in[6];
  const float* Whh0    = (const float*)d_in[7];
  const float* bih0    = (const float*)d_in[8];
  const float* bhh0    = (const float*)d_in[9];
  const float* Wih1    = (const float*)d_in[10];
  const float* Whh1    = (const float*)d_in[11];
  const float* bih1    = (const float*)d_in[12];
  const float* bhh1    = (const float*)d_in[13];
  const float* Wih2    = (const float*)d_in[14];
  const float* Whh2    = (const float*)d_in[15];
  const float* bih2    = (const float*)d_in[16];
  const float* bhh2    = (const float*)d_in[17];
  const float* Wproj   = (const float*)d_in[18];
  const float* bproj   = (const float*)d_in[19];

  float* ws = (float*)d_ws;
  float* out = (float*)d_out;

  int setup_threads = WS_FLOATS;
  int setup_blocks = (setup_threads + 255) / 256;
  setup_kernel<<<setup_blocks, 256, 0, stream>>>(Whh0, Wih1, Whh1, Wih2, Whh2, Wproj,
                                                Wemb, bemb, Wih0, bih0, ws);

  gru_persist<<<BATCH / RT, NT, 0, stream>>>(latent, tgt, Winit, binit,
                                             bhh0, bih1, bhh1, bih2, bhh2, bproj,
                                             ws, out);
}

// Round 9
// 6777.991 us; speedup vs baseline: 1.6031x; 1.0012x over previous
//
#include <hip/hip_runtime.h>
#include <hip/hip_bf16.h>

// Problem constants
#define BATCH 1024
#define SEQ   350
#define LAT   512
#define VOC   41
#define H0D   512
#define H1D   256
#define H2D   128
#define H3D   32
#define G1    768   // 3*H1D
#define G2    384   // 3*H2D
#define G3    96    // 3*H3D
#define SOS   1

// ws layout (floats) — PLANAR, identical to rounds 2/7 (proven L2-resident)
#define O_HH0   0         // wt_hh0 [256][768]   (k-major, gate planes at +0/+256/+512)
#define O_IH1   196608    // wt_ih1 [256][384]
#define O_HH1   294912    // wt_hh1 [128][384]
#define O_IH2   344064    // wt_ih2 [128][96]
#define O_HH2   356352    // wt_hh2 [32][96]
#define O_PROJ  359424    // wt_proj [32][41]
#define O_TAB   360736    // gi0 table [41][768]
#define WS_FLOATS 392224

#define RT 4    // batch rows per block
#define NT 512  // threads per block (8 waves)

__global__ void setup_kernel(const float* __restrict__ Whh0, const float* __restrict__ Wih1,
                             const float* __restrict__ Whh1, const float* __restrict__ Wih2,
                             const float* __restrict__ Whh2, const float* __restrict__ Wproj,
                             const float* __restrict__ Wemb, const float* __restrict__ bemb,
                             const float* __restrict__ Wih0, const float* __restrict__ bih0,
                             float* __restrict__ ws) {
  int idx = blockIdx.x * blockDim.x + threadIdx.x;
  if (idx < 196608) { int o = idx % G1, k = idx / G1; ws[O_HH0 + k*G1 + o] = Whh0[o*H1D + k]; return; }
  idx -= 196608;
  if (idx < 98304)  { int o = idx % G2, k = idx / G2; ws[O_IH1 + k*G2 + o] = Wih1[o*H1D + k]; return; }
  idx -= 98304;
  if (idx < 49152)  { int o = idx % G2, k = idx / G2; ws[O_HH1 + k*G2 + o] = Whh1[o*H2D + k]; return; }
  idx -= 49152;
  if (idx < 12288)  { int o = idx % G3, k = idx / G3; ws[O_IH2 + k*G3 + o] = Wih2[o*H2D + k]; return; }
  idx -= 12288;
  if (idx < 3072)   { int o = idx % G3, k = idx / G3; ws[O_HH2 + k*G3 + o] = Whh2[o*H3D + k]; return; }
  idx -= 3072;
  if (idx < 1312)   { int o = idx % VOC, k = idx / VOC; ws[O_PROJ + k*VOC + o] = Wproj[o*H3D + k]; return; }
  idx -= 1312;
  if (idx < 31488) {
    // gi0 table: exact (f64-accumulated) x@Wih0.T + bih0 per token value.
    int o = idx % G1, v = idx / G1;
    double acc = (double)bih0[o];
    const float* wrow = Wih0 + (size_t)o * H0D;
    for (int k = 0; k < H0D; ++k)
      acc += ((double)Wemb[k*VOC + v] + (double)bemb[k]) * (double)wrow[k];
    ws[O_TAB + v*G1 + o] = (float)acc;
  }
}

__device__ __forceinline__ float sigf(float x) { return 1.0f / (1.0f + expf(-x)); }

__global__ __launch_bounds__(NT, 2) void gru_persist(
    const float* __restrict__ latent, const int* __restrict__ tgt,
    const float* __restrict__ Winit, const float* __restrict__ binit,
    const float* __restrict__ bhh0,
    const float* __restrict__ bih1, const float* __restrict__ bhh1,
    const float* __restrict__ bih2, const float* __restrict__ bhh2,
    const float* __restrict__ bproj,
    const float* __restrict__ ws, float* __restrict__ out)
{
  const int tid = threadIdx.x;
  const int r0 = blockIdx.x * RT;
  const int lane = tid & 63;
  const int wv = tid >> 6;   // wave id 0..7

  const float* wt_hh0 = ws + O_HH0;
  const float* wt_ih1 = ws + O_IH1;
  const float* wt_hh1 = ws + O_HH1;
  const float* wt_ih2 = ws + O_IH2;
  const float* wt_hh2 = ws + O_HH2;
  const float* wt_proj = ws + O_PROJ;
  const float* tab = ws + O_TAB;

  float* __restrict__ out_logits = out;
  float* __restrict__ out_pred = out + (size_t)BATCH * SEQ * VOC;

  // h0 double-buffered (stage A has no barrier between dot-reads and epilogue
  // writes anymore); h1/h2 single-buffered exactly as round 7 (B3/B5 separate
  // their readers from writers).
  __shared__ __align__(16) float h0s[2][RT][H1D];  // 8 KB
  __shared__ __align__(16) float h1s[RT][H2D];     // 2 KB
  __shared__ __align__(16) float h2s[RT][H3D];     // 0.5 KB
  __shared__ float scBi[2][RT][3][H2D];   // 12 KB  (gi1 halves)
  __shared__ float scBh[2][RT][3][H2D];   // 12 KB  (gh1 halves)
  __shared__ float scC[10][3][RT][H3D];   // 15 KB  (stage C partials)
  __shared__ float projS[H3D * VOC];      // 5.1 KB
  __shared__ int   toksAll[RT][SEQ];      // 5.5 KB
  // total ~61 KB

  // ---- Stage A wave-local mapping: wave w owns j in [32w,32w+32);
  //      lane-halves = K-halves (identical (j,kh) partials to round 7).
  const int jA  = (wv << 5) + (lane & 31);
  const int kh  = lane >> 5;          // 0/1
  const int kA0 = kh << 7;            // 0 or 128
  const int rbA = kh << 1;            // epilogue rows {0,1} or {2,3}
  // Stage B/C mappings: round 7 verbatim
  const int jb = tid & 127;
  const int g  = tid >> 7;
  const int jc = tid & 31;
  const int sc = tid >> 5;   // 0..15

  // ---- t-invariant f32 biases
  const float bA_r = bhh0[jA], bA_z = bhh0[256 + jA], bA_n = bhh0[512 + jA];
  const float bB_ir = bih1[jb], bB_iz = bih1[128 + jb], bB_in = bih1[256 + jb];
  const float bB_hr = bhh1[jb], bB_hz = bhh1[128 + jb], bB_hn = bhh1[256 + jb];
  const int jj2 = lane & 31;
  const float bC_ir = bih2[jj2], bC_iz = bih2[32 + jj2], bC_in = bih2[64 + jj2];
  const float bC_hr = bhh2[jj2], bC_hz = bhh2[32 + jj2], bC_hn = bhh2[64 + jj2];
  const int cpr = (lane < VOC) ? lane : 0;
  const float bP = bproj[cpr];

  // ---- one-time staging: tokens (SOS at t=0) and projection weights into LDS
  for (int i = tid; i < RT * SEQ; i += NT) {
    int r = i / SEQ, tt = i - r * SEQ;
    toksAll[r][tt] = (tt == 0) ? SOS : tgt[(size_t)(r0 + r) * SEQ + tt];
  }
  for (int i = tid; i < H3D * VOC; i += NT) projS[i] = wt_proj[i];

  // ---- init hidden states (f64, one-time; exact early-step logits)
  for (int idx = tid; idx < RT * 416; idx += NT) {
    int r = idx / 416, jj = idx - r * 416;
    const float* lrow = latent + (size_t)(r0 + r) * LAT;
    const float* wrow = Winit + (size_t)jj * LAT;
    double acc = (double)binit[jj];
    for (int k = 0; k < LAT; ++k) acc += (double)lrow[k] * (double)wrow[k];
    float a = (float)acc;
    if (jj < H1D) h0s[0][r][jj] = a;
    else if (jj < H1D + H2D) h1s[r][jj - H1D] = a;
    else h2s[r][jj - H1D - H2D] = a;
  }
  __syncthreads();

  int cur0 = 0;

  for (int t = 0; t < SEQ; ++t) {
    // ======== Stage A: GRU0, wave-local (bit-exact round-7 arithmetic).
    //          Dot reads h0s[cur0]; epilogue writes h0s[cur0^1] (disjoint). ========
    {
      const float* trow0 = tab + (size_t)toksAll[rbA][t] * G1;
      const float* trow1 = tab + (size_t)toksAll[rbA + 1][t] * G1;
      const float t0x = trow0[jA], t0y = trow0[256 + jA], t0z = trow0[512 + jA];
      const float t1x = trow1[jA], t1y = trow1[256 + jA], t1z = trow1[512 + jA];

      float aR[RT], aZ[RT], aN[RT];
      #pragma unroll
      for (int r = 0; r < RT; ++r) { aR[r] = 0.0f; aZ[r] = 0.0f; aN[r] = 0.0f; }
      const float* __restrict__ wbase = wt_hh0 + jA;
      for (int kb = kA0; kb < kA0 + 128; kb += 4) {
        float4 hv[RT];
        #pragma unroll
        for (int r = 0; r < RT; ++r) hv[r] = *(const float4*)&h0s[cur0][r][kb];
        #pragma unroll
        for (int u = 0; u < 4; ++u) {
          const float* wp = wbase + (size_t)(kb + u) * G1;
          const float wr = wp[0], wz = wp[256], wn = wp[512];
          #pragma unroll
          for (int r = 0; r < RT; ++r) {
            const float hval = ((const float*)&hv[r])[u];
            aR[r] = fmaf(hval, wr, aR[r]);
            aZ[r] = fmaf(hval, wz, aZ[r]);
            aN[r] = fmaf(hval, wn, aN[r]);
          }
        }
      }
      // other K-half via shfl (replaces scA + B1); all 64 lanes participate.
      float oR[RT], oZ[RT], oN[RT];
      #pragma unroll
      for (int r = 0; r < RT; ++r) {
        oR[r] = __shfl_xor(aR[r], 32);
        oZ[r] = __shfl_xor(aZ[r], 32);
        oN[r] = __shfl_xor(aN[r], 32);
      }
      // Epilogue, association identical to round 7: ((tx + own) + other) + b.
      // lanes<32 (own=half0) -> rows 0,1 ; lanes>=32 (own=half1) -> rows 2,3.
#define EPIA(r, tx, ty, tz)                                                \
      {                                                                    \
        const float gR  = tx + aR[r] + oR[r] + bA_r;                       \
        const float gZ  = ty + aZ[r] + oZ[r] + bA_z;                       \
        const float ghN =      aN[r] + oN[r] + bA_n;                       \
        const float rg = sigf(gR);                                         \
        const float zg = sigf(gZ);                                         \
        const float ng = tanhf(fmaf(rg, ghN, tz));                         \
        h0s[cur0 ^ 1][r][jA] = (1.0f - zg) * ng + zg * h0s[cur0][r][jA];   \
      }
      if (lane < 32) {
        EPIA(0, t0x, t0y, t0z)
        EPIA(1, t1x, t1y, t1z)
      } else {
        EPIA(2, t0x, t0y, t0z)
        EPIA(3, t1x, t1y, t1z)
      }
#undef EPIA
    }
    __syncthreads();  // B2: h0 new (h0s[cur0^1]) visible to all

    // ======== Stage B: GRU1 — round 7 verbatim. g0,g1 = gi1 K-halves (new h0),
    //          g2,g3 = gh1 K-halves (old h1). Epilogue on g2/g3. ========
    {
      float bR[RT], bZ[RT], bN[RT];
      #pragma unroll
      for (int r = 0; r < RT; ++r) { bR[r] = 0.0f; bZ[r] = 0.0f; bN[r] = 0.0f; }
      if (g < 2) {
        const float* __restrict__ wbase = wt_ih1 + jb;
        const int k0 = g * 128;
        for (int kb = k0; kb < k0 + 128; kb += 4) {
          float4 hv[RT];
          #pragma unroll
          for (int r = 0; r < RT; ++r) hv[r] = *(const float4*)&h0s[cur0 ^ 1][r][kb];
          #pragma unroll
          for (int u = 0; u < 4; ++u) {
            const float* wp = wbase + (size_t)(kb + u) * G2;
            const float wr = wp[0], wz = wp[128], wn = wp[256];
            #pragma unroll
            for (int r = 0; r < RT; ++r) {
              const float hval = ((const float*)&hv[r])[u];
              bR[r] = fmaf(hval, wr, bR[r]);
              bZ[r] = fmaf(hval, wz, bZ[r]);
              bN[r] = fmaf(hval, wn, bN[r]);
            }
          }
        }
        #pragma unroll
        for (int r = 0; r < RT; ++r) {
          scBi[g][r][0][jb] = bR[r];
          scBi[g][r][1][jb] = bZ[r];
          scBi[g][r][2][jb] = bN[r];
        }
      } else {
        const float* __restrict__ wbase = wt_hh1 + jb;
        const int k0 = (g - 2) * 64;
        for (int kb = k0; kb < k0 + 64; kb += 4) {
          float4 hv[RT];
          #pragma unroll
          for (int r = 0; r < RT; ++r) hv[r] = *(const float4*)&h1s[r][kb];
          #pragma unroll
          for (int u = 0; u < 4; ++u) {
            const float* wp = wbase + (size_t)(kb + u) * G2;
            const float wr = wp[0], wz = wp[128], wn = wp[256];
            #pragma unroll
            for (int r = 0; r < RT; ++r) {
              const float hval = ((const float*)&hv[r])[u];
              bR[r] = fmaf(hval, wr, bR[r]);
              bZ[r] = fmaf(hval, wz, bZ[r]);
              bN[r] = fmaf(hval, wn, bN[r]);
            }
          }
        }
        #pragma unroll
        for (int r = 0; r < RT; ++r) {
          scBh[g - 2][r][0][jb] = bR[r];
          scBh[g - 2][r][1][jb] = bZ[r];
          scBh[g - 2][r][2][jb] = bN[r];
        }
      }
      __syncthreads();  // B3: partials visible; all h1s reads done
      if (g >= 2) {
        const int rb = (g - 2) * 2;
        const int oh = 3 - g;   // other gh half's scBh slot
        #pragma unroll
        for (int e = 0; e < 2; ++e) {
          const int r = rb + e;
          const float giR = scBi[0][r][0][jb] + scBi[1][r][0][jb] + bB_ir;
          const float giZ = scBi[0][r][1][jb] + scBi[1][r][1][jb] + bB_iz;
          const float giN = scBi[0][r][2][jb] + scBi[1][r][2][jb] + bB_in;
          const float ghR = bR[r] + scBh[oh][r][0][jb] + bB_hr;
          const float ghZ = bZ[r] + scBh[oh][r][1][jb] + bB_hz;
          const float ghN = bN[r] + scBh[oh][r][2][jb] + bB_hn;
          const float rg = sigf(giR + ghR);
          const float zg = sigf(giZ + ghZ);
          const float ng = tanhf(fmaf(rg, ghN, giN));
          h1s[r][jb] = (1.0f - zg) * ng + zg * h1s[r][jb];
        }
      }
    }
    __syncthreads();  // B4: h1 new visible

    // ======== Stage C: GRU2 — round 7 verbatim. sc0..7 = gi2 slices (new h1),
    //          sc8,9 = gh2 slices (old h2). ========
    {
      float cR[RT], cZ[RT], cN[RT];
      #pragma unroll
      for (int r = 0; r < RT; ++r) { cR[r] = 0.0f; cZ[r] = 0.0f; cN[r] = 0.0f; }
      if (sc < 8) {
        for (int kk = 0; kk < 16; ++kk) {
          int k = sc * 16 + kk;
          const float* wp = wt_ih2 + (size_t)k * G3;
          const float wr = wp[jc], wz = wp[32 + jc], wn = wp[64 + jc];
          #pragma unroll
          for (int r = 0; r < RT; ++r) {
            const float hval = h1s[r][k];
            cR[r] = fmaf(hval, wr, cR[r]);
            cZ[r] = fmaf(hval, wz, cZ[r]);
            cN[r] = fmaf(hval, wn, cN[r]);
          }
        }
      } else if (sc < 10) {
        for (int kk = 0; kk < 16; ++kk) {
          int k = (sc - 8) * 16 + kk;
          const float* wp = wt_hh2 + (size_t)k * G3;
          const float wr = wp[jc], wz = wp[32 + jc], wn = wp[64 + jc];
          #pragma unroll
          for (int r = 0; r < RT; ++r) {
            const float hval = h2s[r][k];
            cR[r] = fmaf(hval, wr, cR[r]);
            cZ[r] = fmaf(hval, wz, cZ[r]);
            cN[r] = fmaf(hval, wn, cN[r]);
          }
        }
      }
      if (sc < 10) {
        #pragma unroll
        for (int r = 0; r < RT; ++r) {
          scC[sc][0][r][jc] = cR[r];
          scC[sc][1][r][jc] = cZ[r];
          scC[sc][2][r][jc] = cN[r];
        }
      }
    }
    __syncthreads();  // B5: scC partials visible; all h2s(old) reads done

    // ======== Stage C combine + projection + argmax, waves 0-3 (one row each);
    //          waves 4-7 fall through into stage A of t+1 (sync via B2(t+1)). ========
    if (wv < 4) {
      const int r = wv;
      float h2f = 0.0f;
      if (lane < 32) {
        const int jj = lane;
        float giR = bC_ir, giZ = bC_iz, giN = bC_in;
        #pragma unroll
        for (int s = 0; s < 8; ++s) {
          giR += scC[s][0][r][jj];
          giZ += scC[s][1][r][jj];
          giN += scC[s][2][r][jj];
        }
        const float ghR = scC[8][0][r][jj] + scC[9][0][r][jj] + bC_hr;
        const float ghZ = scC[8][1][r][jj] + scC[9][1][r][jj] + bC_hz;
        const float ghN = scC[8][2][r][jj] + scC[9][2][r][jj] + bC_hn;
        const float rg = sigf(giR + ghR);
        const float zg = sigf(giZ + ghZ);
        const float ng = tanhf(fmaf(rg, ghN, giN));
        h2f = (1.0f - zg) * ng + zg * h2s[r][jj];
        h2s[r][jj] = h2f;   // next reader (sc8,9 at t+1) crosses B2(t+1)+B4(t+1)
      }
      // projection: lane c computes logit c; h2 broadcast from lanes 0..31
      float acc = bP;
      #pragma unroll
      for (int k = 0; k < H3D; ++k) {
        const float hk = __shfl(h2f, k);
        acc = fmaf(hk, projS[k * VOC + cpr], acc);
      }
      if (lane < VOC)
        out_logits[((size_t)(r0 + r) * SEQ + t) * VOC + lane] = acc;
      // wave-wide argmax, first-max tie-break to match jnp.argmax
      float val = (lane < VOC) ? acc : -3.402823466e38f;
      int idx = lane;
      #pragma unroll
      for (int off = 32; off > 0; off >>= 1) {
        const float ov = __shfl_xor(val, off);
        const int   oi = __shfl_xor(idx, off);
        if (ov > val || (ov == val && oi < idx)) { val = ov; idx = oi; }
      }
      if (lane == 0)
        out_pred[(size_t)(r0 + r) * SEQ + t] = (float)idx;
    }
    cur0 ^= 1;
    // Hazard audit (4 barriers/step):
    //  h0s[cur0] (dot-read buffer): written next by A(t+1) epilogue — its last
    //    readers (A(t) dot + epilogue-old-read) finished before B2(t); A(t+1)
    //    runs after B5(t) — >=3 barriers apart. Within A: dot reads [cur0],
    //    epilogue writes [cur0^1] — disjoint buffers, no barrier needed.
    //  h0s[cur0^1]: written by A(t) epilogue before B2(t); read by B(t) gi1
    //    after B2(t) and by A(t+1) dot (waves 4-7 early, after B5(t)) — OK.
    //  h1s: gh1 reads before B3(t); epilogue writes after B3(t) (in-place, as
    //    round 7); stage C reads after B4(t); B(t+1) writes after B3(t+1) — OK.
    //  scBi/scBh: W before B3 / R after B3; next W after B2(t+1) — OK.
    //  h2s: combine writes after B5(t); sc8,9 read at t+1 after B2,B4(t+1) — OK.
    //  scC: W before B5 / R after B5; next W after B4(t+1) — OK.
    //  Shfl uniformity: stage A merge + stage C proj/argmax execute on all 64
    //    lanes of their waves (branches only around non-shfl code) — OK.
  }
}

extern "C" void kernel_launch(void* const* d_in, const int* in_sizes, int n_in,
                              void* d_out, int out_size, void* d_ws, size_t ws_size,
                              hipStream_t stream) {
  const float* latent  = (const float*)d_in[0];
  const int*   tgt     = (const int*)d_in[1];
  const float* Wemb    = (const float*)d_in[2];
  const float* bemb    = (const float*)d_in[3];
  const float* Winit   = (const float*)d_in[4];
  const float* binit   = (const float*)d_in[5];
  const float* Wih0    = (const float*)d_in[6];
  const float* Whh0    = (const float*)d_in[7];
  const float* bih0    = (const float*)d_in[8];
  const float* bhh0    = (const float*)d_in[9];
  const float* Wih1    = (const float*)d_in[10];
  const float* Whh1    = (const float*)d_in[11];
  const float* bih1    = (const float*)d_in[12];
  const float* bhh1    = (const float*)d_in[13];
  const float* Wih2    = (const float*)d_in[14];
  const float* Whh2    = (const float*)d_in[15];
  const float* bih2    = (const float*)d_in[16];
  const float* bhh2    = (const float*)d_in[17];
  const float* Wproj   = (const float*)d_in[18];
  const float* bproj   = (const float*)d_in[19];

  float* ws = (float*)d_ws;
  float* out = (float*)d_out;

  int setup_threads = WS_FLOATS;
  int setup_blocks = (setup_threads + 255) / 256;
  setup_kernel<<<setup_blocks, 256, 0, stream>>>(Whh0, Wih1, Whh1, Wih2, Whh2, Wproj,
                                                Wemb, bemb, Wih0, bih0, ws);

  gru_persist<<<BATCH / RT, NT, 0, stream>>>(latent, tgt, Winit, binit,
                                             bhh0, bih1, bhh1, bih2, bhh2, bproj,
                                             ws, out);
}